// Round 11
// baseline (394.392 us; speedup 1.0000x reference)
//
#include <hip/hip_runtime.h>
#include <hip/hip_cooperative_groups.h>
#include <hip/hip_bf16.h>
#include <math.h>

namespace cg = cooperative_groups;

// GQA attention forward, MI355X. Round 11: single cooperative kernel.
// Stages (3x grid.sync between): prep (weights transpose + input bf16 cvt),
// proj (unified QKV GEMM + RoPE), attn (r9-style flash, dbuf, packed-P,
// key-permuted V), oproj. 512 blocks x 256 thr, LDS 46.6 KB union.
// ws (u16): Xq 2M | Xk 2M | Xv 2M | Wt 1.5M | wot 1M | Qr 2M | Kr 512K | Vrt 512K | AO 2M

#define SEQ 2048
#define DM 1024
#define HD 64

using u16 = unsigned short;
typedef __attribute__((ext_vector_type(8))) short bf16x8;
typedef __attribute__((ext_vector_type(4))) float f32x4;

// 1/sqrt(64) * log2(e): softmax in exp2 domain.
#define QSCALE 0.18033688011112042f

__device__ __forceinline__ u16 f2b(float f) {              // RNE
    union { float f; unsigned int i; } v; v.f = f;
    unsigned int u = v.i;
    return (u16)((u + 0x7fffu + ((u >> 16) & 1u)) >> 16);
}
__device__ __forceinline__ u16 f2b_fast(float f) {         // biased round
    union { float f; unsigned int i; } v; v.f = f;
    return (u16)((v.i + 0x8000u) >> 16);
}

__global__ __launch_bounds__(256, 2) void fused_kernel(
    const float* __restrict__ qin, const float* __restrict__ kin, const float* __restrict__ vin,
    const float* __restrict__ Wq, const float* __restrict__ Wk,
    const float* __restrict__ Wv, const float* __restrict__ Wo,
    const float* __restrict__ bq, const float* __restrict__ bk,
    const float* __restrict__ bv, const float* __restrict__ bo,
    u16* __restrict__ Xq, u16* __restrict__ Xk, u16* __restrict__ Xv,
    u16* __restrict__ Wt, u16* __restrict__ wot,
    u16* __restrict__ Qr, u16* __restrict__ Kr, u16* __restrict__ Vrt,
    u16* __restrict__ AO, float* __restrict__ out)
{
    cg::grid_group grid = cg::this_grid();

    __shared__ __align__(16) u16 smem[23296];    // 46592 B union

    const int bid = blockIdx.x;                  // 0..511
    const int t = threadIdx.x;
    const int w = t >> 6, lane = t & 63, lm = lane & 15, quad = lane >> 4;

    // ================================================== stage 0: prep
    {
        short (*T)[72] = (short(*)[72])smem;
        for (int u = bid; u < 1408; u += 512) {
            __syncthreads();
            if (u < 640) {   // weights: 64x64 transpose fp32 -> bf16 [n][k]
                const float* W; u16* dst; int N, t0, rowoff;
                if (u < 256)      { W = Wq; dst = Wt;  N = 1024; t0 = u;       rowoff = 0; }
                else if (u < 320) { W = Wk; dst = Wt;  N = 256;  t0 = u - 256; rowoff = 1024; }
                else if (u < 384) { W = Wv; dst = Wt;  N = 256;  t0 = u - 320; rowoff = 1280; }
                else              { W = Wo; dst = wot; N = 1024; t0 = u - 384; rowoff = 0; }
                const int ntn = N >> 6;
                const int k0 = (t0 / ntn) * 64, n0 = (t0 % ntn) * 64;
                const int r = t >> 4, c4 = (t & 15) * 4;
                #pragma unroll
                for (int rr = 0; rr < 4; ++rr) {
                    const int k = r + rr * 16;
                    float4 w4 = *reinterpret_cast<const float4*>(W + (size_t)(k0 + k) * N + n0 + c4);
                    T[c4 + 0][k] = (short)f2b(w4.x);
                    T[c4 + 1][k] = (short)f2b(w4.y);
                    T[c4 + 2][k] = (short)f2b(w4.z);
                    T[c4 + 3][k] = (short)f2b(w4.w);
                }
                __syncthreads();
                const int n = t >> 2, ck = (t & 3) * 16;
                u16* dp = dst + (size_t)(rowoff + n0 + n) * DM + k0 + ck;
                *reinterpret_cast<bf16x8*>(dp)     = *reinterpret_cast<const bf16x8*>(&T[n][ck]);
                *reinterpret_cast<bf16x8*>(dp + 8) = *reinterpret_cast<const bf16x8*>(&T[n][ck + 8]);
            } else {          // inputs: fp32 -> bf16 row-major
                const int idx = u - 640;
                const int which = idx >> 8;
                const int ib = idx & 255;
                const float* src = (which == 0) ? qin : (which == 1) ? kin : vin;
                u16* dst = (which == 0) ? Xq : (which == 1) ? Xk : Xv;
                const size_t base = (size_t)ib * 8192 + (size_t)t * 32;
                #pragma unroll
                for (int c = 0; c < 4; ++c) {
                    float4 x0 = *reinterpret_cast<const float4*>(src + base + c * 8);
                    float4 x1 = *reinterpret_cast<const float4*>(src + base + c * 8 + 4);
                    bf16x8 o;
                    o[0] = (short)f2b(x0.x); o[1] = (short)f2b(x0.y);
                    o[2] = (short)f2b(x0.z); o[3] = (short)f2b(x0.w);
                    o[4] = (short)f2b(x1.x); o[5] = (short)f2b(x1.y);
                    o[6] = (short)f2b(x1.z); o[7] = (short)f2b(x1.w);
                    *reinterpret_cast<bf16x8*>(dst + base + c * 8) = o;
                }
            }
        }
    }
    grid.sync();

    // ================================================== stage 1: proj
    {
        u16 (*As)[64][72] = (u16(*)[64][72])smem;          // [2][64][72]
        u16 (*Bs)[64][72] = (u16(*)[64][72])(smem + 9216);
        const int sr = t >> 2, sc = (t & 3) * 16;

        for (int u = bid; u < 768; u += 512) {
            __syncthreads();
            const int n0 = (u % 24) * 64, m0 = (u / 24) * 64;
            const int zone = (n0 < 1024) ? 0 : (n0 < 1280) ? 1 : 2;
            const u16* __restrict__ Az = (zone == 0) ? Xq : (zone == 1) ? Xk : Xv;

            f32x4 acc[4] = { {0,0,0,0}, {0,0,0,0}, {0,0,0,0}, {0,0,0,0} };

            const u16* ap_ = Az + (size_t)(m0 + sr) * DM + sc;
            const u16* bp_ = Wt + (size_t)(n0 + sr) * DM + sc;
            bf16x8 aR0 = *reinterpret_cast<const bf16x8*>(ap_);
            bf16x8 aR1 = *reinterpret_cast<const bf16x8*>(ap_ + 8);
            bf16x8 bR0 = *reinterpret_cast<const bf16x8*>(bp_);
            bf16x8 bR1 = *reinterpret_cast<const bf16x8*>(bp_ + 8);

            for (int k0 = 0; k0 < DM; k0 += 64) {
                const int buf = (k0 >> 6) & 1;
                *reinterpret_cast<bf16x8*>(&As[buf][sr][sc])     = aR0;
                *reinterpret_cast<bf16x8*>(&As[buf][sr][sc + 8]) = aR1;
                *reinterpret_cast<bf16x8*>(&Bs[buf][sr][sc])     = bR0;
                *reinterpret_cast<bf16x8*>(&Bs[buf][sr][sc + 8]) = bR1;
                if (k0 + 64 < DM) {
                    aR0 = *reinterpret_cast<const bf16x8*>(ap_ + k0 + 64);
                    aR1 = *reinterpret_cast<const bf16x8*>(ap_ + k0 + 72);
                    bR0 = *reinterpret_cast<const bf16x8*>(bp_ + k0 + 64);
                    bR1 = *reinterpret_cast<const bf16x8*>(bp_ + k0 + 72);
                }
                __syncthreads();     // single barrier (dbuf-safe)
                bf16x8 af0 = *reinterpret_cast<const bf16x8*>(&As[buf][16 * w + lm][quad * 8]);
                bf16x8 af1 = *reinterpret_cast<const bf16x8*>(&As[buf][16 * w + lm][32 + quad * 8]);
                #pragma unroll
                for (int nb = 0; nb < 4; ++nb) {
                    bf16x8 b0 = *reinterpret_cast<const bf16x8*>(&Bs[buf][16 * nb + lm][quad * 8]);
                    bf16x8 b1 = *reinterpret_cast<const bf16x8*>(&Bs[buf][16 * nb + lm][32 + quad * 8]);
                    acc[nb] = __builtin_amdgcn_mfma_f32_16x16x32_bf16(af0, b0, acc[nb], 0, 0, 0);
                    acc[nb] = __builtin_amdgcn_mfma_f32_16x16x32_bf16(af1, b1, acc[nb], 0, 0, 0);
                }
            }

            const float* __restrict__ bias = (zone == 0) ? bq : (zone == 1) ? bk : bv;
            const int nbase = (zone == 0) ? n0 : (zone == 1) ? (n0 - 1024) : (n0 - 1280);
            const int head = nbase >> 6;
            #pragma unroll
            for (int nb = 0; nb < 4; ++nb) {
                const int d = 16 * nb + lm;
                const float bvv = bias[nbase + d];
                float vals[4];
                #pragma unroll
                for (int r = 0; r < 4; ++r) vals[r] = acc[nb][r] + bvv;
                if (zone != 2) {
                    const int pi = d >> 1;
                    const float theta = exp2f(-0.8304820237f * (float)pi);  // 10000^(-pi/16)
                    const bool odd = (lm & 1);
                    const float sca = (zone == 0) ? QSCALE : 1.0f;
                    u16* op = (zone == 0 ? Qr : Kr) + (size_t)head * SEQ * HD;
                    #pragma unroll
                    for (int r = 0; r < 4; ++r) {
                        const int m = m0 + 16 * w + quad * 4 + r;
                        float sn, cs;
                        sincosf((float)m * theta, &sn, &cs);
                        float x  = vals[r];
                        float xp = __shfl_xor(x, 1);
                        float o  = (odd ? (xp * sn + x * cs) : (x * cs - xp * sn)) * sca;
                        op[(size_t)m * HD + d] = f2b(o);
                    }
                } else {
                    // V transposed [kvh][d][pos], key-permuted per 64-tile:
                    // within = m&63 -> pos = tile*64 + 4*(within&15) + (within>>4)
                    u16* vp = Vrt + ((size_t)head * HD + d) * SEQ;
                    #pragma unroll
                    for (int r = 0; r < 4; ++r) {
                        const int m = m0 + 16 * w + quad * 4 + r;
                        const int within = m & 63;
                        const int pos = (m & ~63) + 4 * (within & 15) + (within >> 4);
                        vp[pos] = f2b(vals[r]);
                    }
                }
            }
        }
    }
    grid.sync();

    // ================================================== stage 2: attn
    {
        u16 (*Ks)[64][72] = (u16(*)[64][72])smem;          // [2][64][72]
        u16 (*Vt)[64][72] = (u16(*)[64][72])(smem + 9216);
        u16 (*Ps)[16][76] = (u16(*)[16][76])(smem + 18432); // [4][16][76]

        const int h = bid & 15;
        const int idx = bid >> 4;
        const int qt = (idx < 16) ? idx : 47 - idx;    // b and b+256 sum to 31
        const int kvh = h & 3;

        // Q fragments direct from global (L2-hot after grid.sync)
        const u16* qp = Qr + ((size_t)h * SEQ + qt * 64 + 16 * w + lm) * HD + quad * 8;
        const bf16x8 aq0 = *reinterpret_cast<const bf16x8*>(qp);
        const bf16x8 aq1 = *reinterpret_cast<const bf16x8*>(qp + 32);

        f32x4 O[4] = { {0,0,0,0}, {0,0,0,0}, {0,0,0,0}, {0,0,0,0} };
        float lp[4] = { 0.f, 0.f, 0.f, 0.f };

        const int sr = t >> 2, sc = (t & 3) * 16;
        const u16* kb_ = Kr  + ((size_t)kvh * SEQ + sr) * HD + sc;   // + key*HD
        const u16* vb_ = Vrt + ((size_t)kvh * HD + sr) * SEQ + sc;   // + pos
        bf16x8 kR0 = *reinterpret_cast<const bf16x8*>(kb_);
        bf16x8 kR1 = *reinterpret_cast<const bf16x8*>(kb_ + 8);
        bf16x8 vR0 = *reinterpret_cast<const bf16x8*>(vb_);
        bf16x8 vR1 = *reinterpret_cast<const bf16x8*>(vb_ + 8);

        u16* ps = &Ps[w][0][0];

        for (int kt = 0; kt <= qt; ++kt) {
            const int buf = kt & 1;
            *reinterpret_cast<bf16x8*>(&Ks[buf][sr][sc])     = kR0;
            *reinterpret_cast<bf16x8*>(&Ks[buf][sr][sc + 8]) = kR1;
            *reinterpret_cast<bf16x8*>(&Vt[buf][sr][sc])     = vR0;
            *reinterpret_cast<bf16x8*>(&Vt[buf][sr][sc + 8]) = vR1;
            if (kt < qt) {
                const u16* kp = kb_ + (size_t)(kt + 1) * 64 * HD;
                const u16* vp = vb_ + (size_t)(kt + 1) * 64;
                kR0 = *reinterpret_cast<const bf16x8*>(kp);
                kR1 = *reinterpret_cast<const bf16x8*>(kp + 8);
                vR0 = *reinterpret_cast<const bf16x8*>(vp);
                vR1 = *reinterpret_cast<const bf16x8*>(vp + 8);
            }
            __syncthreads();     // single barrier (dbuf-safe)

            f32x4 s[4];
            #pragma unroll
            for (int nb = 0; nb < 4; ++nb) {
                bf16x8 b0 = *reinterpret_cast<const bf16x8*>(&Ks[buf][16 * nb + lm][quad * 8]);
                bf16x8 b1 = *reinterpret_cast<const bf16x8*>(&Ks[buf][16 * nb + lm][32 + quad * 8]);
                f32x4 zz = { 0.f, 0.f, 0.f, 0.f };
                zz = __builtin_amdgcn_mfma_f32_16x16x32_bf16(aq0, b0, zz, 0, 0, 0);
                s[nb] = __builtin_amdgcn_mfma_f32_16x16x32_bf16(aq1, b1, zz, 0, 0, 0);
            }

            if (kt == qt) {   // causal mask (col=16nb+lm, row=16w+quad*4+r)
                #pragma unroll
                for (int nb = 0; nb < 4; ++nb)
                    #pragma unroll
                    for (int r = 0; r < 4; ++r)
                        if (16 * nb + lm > 16 * w + quad * 4 + r) s[nb][r] = -INFINITY;
            }

            // exp2 + packed P: row quad*4+r, cols 4*lm..4*lm+3 (nb)
            #pragma unroll
            for (int r = 0; r < 4; ++r) {
                u16 pk[4];
                #pragma unroll
                for (int nb = 0; nb < 4; ++nb) {
                    float e = __builtin_amdgcn_exp2f(fminf(s[nb][r], 126.f));
                    lp[r] += e;
                    pk[nb] = f2b_fast(e);
                }
                *reinterpret_cast<uint2*>(&ps[(quad * 4 + r) * 76 + 4 * lm]) =
                    *reinterpret_cast<uint2*>(pk);
            }

            const bf16x8 ap0 = *reinterpret_cast<const bf16x8*>(&ps[lm * 76 + quad * 8]);
            const bf16x8 ap1 = *reinterpret_cast<const bf16x8*>(&ps[lm * 76 + 32 + quad * 8]);
            #pragma unroll
            for (int db = 0; db < 4; ++db) {
                bf16x8 v0 = *reinterpret_cast<const bf16x8*>(&Vt[buf][16 * db + lm][quad * 8]);
                bf16x8 v1 = *reinterpret_cast<const bf16x8*>(&Vt[buf][16 * db + lm][32 + quad * 8]);
                O[db] = __builtin_amdgcn_mfma_f32_16x16x32_bf16(ap0, v0, O[db], 0, 0, 0);
                O[db] = __builtin_amdgcn_mfma_f32_16x16x32_bf16(ap1, v1, O[db], 0, 0, 0);
            }
        }

        #pragma unroll
        for (int r = 0; r < 4; ++r) {
            #pragma unroll
            for (int off = 1; off < 16; off <<= 1)
                lp[r] += __shfl_xor(lp[r], off);
            const float inv = 1.0f / lp[r];
            const size_t orow = (size_t)(qt * 64 + 16 * w + quad * 4 + r) * DM + (size_t)h * HD;
            #pragma unroll
            for (int db = 0; db < 4; ++db)
                AO[orow + 16 * db + lm] = f2b(O[db][r] * inv);
        }
    }
    grid.sync();

    // ================================================== stage 3: oproj
    {
        u16 (*As)[64][72] = (u16(*)[64][72])smem;
        u16 (*Bs)[64][72] = (u16(*)[64][72])(smem + 9216);
        const int sr = t >> 2, sc = (t & 3) * 16;
        const int n0 = (bid & 15) * 64, m0 = (bid >> 4) * 64;

        f32x4 acc[4] = { {0,0,0,0}, {0,0,0,0}, {0,0,0,0}, {0,0,0,0} };

        const u16* ap_ = AO  + (size_t)(m0 + sr) * DM + sc;
        const u16* bp_ = wot + (size_t)(n0 + sr) * DM + sc;
        bf16x8 aR0 = *reinterpret_cast<const bf16x8*>(ap_);
        bf16x8 aR1 = *reinterpret_cast<const bf16x8*>(ap_ + 8);
        bf16x8 bR0 = *reinterpret_cast<const bf16x8*>(bp_);
        bf16x8 bR1 = *reinterpret_cast<const bf16x8*>(bp_ + 8);

        for (int k0 = 0; k0 < DM; k0 += 64) {
            const int buf = (k0 >> 6) & 1;
            *reinterpret_cast<bf16x8*>(&As[buf][sr][sc])     = aR0;
            *reinterpret_cast<bf16x8*>(&As[buf][sr][sc + 8]) = aR1;
            *reinterpret_cast<bf16x8*>(&Bs[buf][sr][sc])     = bR0;
            *reinterpret_cast<bf16x8*>(&Bs[buf][sr][sc + 8]) = bR1;
            if (k0 + 64 < DM) {
                aR0 = *reinterpret_cast<const bf16x8*>(ap_ + k0 + 64);
                aR1 = *reinterpret_cast<const bf16x8*>(ap_ + k0 + 72);
                bR0 = *reinterpret_cast<const bf16x8*>(bp_ + k0 + 64);
                bR1 = *reinterpret_cast<const bf16x8*>(bp_ + k0 + 72);
            }
            __syncthreads();
            bf16x8 af0 = *reinterpret_cast<const bf16x8*>(&As[buf][16 * w + lm][quad * 8]);
            bf16x8 af1 = *reinterpret_cast<const bf16x8*>(&As[buf][16 * w + lm][32 + quad * 8]);
            #pragma unroll
            for (int nb = 0; nb < 4; ++nb) {
                bf16x8 b0 = *reinterpret_cast<const bf16x8*>(&Bs[buf][16 * nb + lm][quad * 8]);
                bf16x8 b1 = *reinterpret_cast<const bf16x8*>(&Bs[buf][16 * nb + lm][32 + quad * 8]);
                acc[nb] = __builtin_amdgcn_mfma_f32_16x16x32_bf16(af0, b0, acc[nb], 0, 0, 0);
                acc[nb] = __builtin_amdgcn_mfma_f32_16x16x32_bf16(af1, b1, acc[nb], 0, 0, 0);
            }
        }

        #pragma unroll
        for (int nb = 0; nb < 4; ++nb) {
            const int dl = 16 * nb + lm;
            const float bvv = bo[n0 + dl];
            #pragma unroll
            for (int r = 0; r < 4; ++r) {
                const int m = m0 + 16 * w + quad * 4 + r;
                out[(size_t)m * DM + n0 + dl] = acc[nb][r] + bvv;
            }
        }
    }
}

// ---------------------------------------------------------------- launcher
extern "C" void kernel_launch(void* const* d_in, const int* in_sizes, int n_in,
                              void* d_out, int out_size, void* d_ws, size_t ws_size,
                              hipStream_t stream)
{
    const float* q  = (const float*)d_in[0];
    const float* k  = (const float*)d_in[1];
    const float* v  = (const float*)d_in[2];
    // d_in[3] = mask (int32) — causal tril, handled analytically
    const float* Wq = (const float*)d_in[4];
    const float* bq = (const float*)d_in[5];
    const float* Wk = (const float*)d_in[6];
    const float* bk = (const float*)d_in[7];
    const float* Wv = (const float*)d_in[8];
    const float* bv = (const float*)d_in[9];
    const float* Wo = (const float*)d_in[10];
    const float* bo = (const float*)d_in[11];
    float* out = (float*)d_out;

    u16* Xq  = (u16*)d_ws;                          // [2048][1024] bf16
    u16* Xk  = Xq  + (size_t)SEQ * DM;
    u16* Xv  = Xk  + (size_t)SEQ * DM;
    u16* Wt  = Xv  + (size_t)SEQ * DM;              // [1536][1024]
    u16* wot = Wt  + (size_t)1536 * 1024;           // [1024][1024]
    u16* Qr  = wot + (size_t)1024 * 1024;           // [16][2048][64]
    u16* Kr  = Qr  + (size_t)16 * SEQ * HD;         // [4][2048][64]
    u16* Vrt = Kr  + (size_t)4 * SEQ * HD;          // [4][64][2048] key-permuted
    u16* AO  = Vrt + (size_t)4 * SEQ * HD;          // [2048][1024]

    void* args[] = {
        (void*)&q, (void*)&k, (void*)&v,
        (void*)&Wq, (void*)&Wk, (void*)&Wv, (void*)&Wo,
        (void*)&bq, (void*)&bk, (void*)&bv, (void*)&bo,
        (void*)&Xq, (void*)&Xk, (void*)&Xv, (void*)&Wt, (void*)&wot,
        (void*)&Qr, (void*)&Kr, (void*)&Vrt, (void*)&AO, (void*)&out
    };
    hipLaunchCooperativeKernel((const void*)fused_kernel, dim3(512), dim3(256),
                               args, 0, stream);
}

// Round 12
// 166.710 us; speedup vs baseline: 2.3657x; 2.3657x over previous
//
#include <hip/hip_runtime.h>
#include <hip/hip_bf16.h>
#include <math.h>

// GQA attention forward, MI355X. Round 12: r9 base (166 us best) with GEMMs
// re-tiled to 64x128 blocks / 32x64 wave tiles (16 MFMA per 12 ds_read_b128,
// was 8 per 10) + single barrier per k-iter. prep/attn are r9-verbatim.
// ws (u16): Xq 2M | Xk 2M | Xv 2M | Wt 1.5M | wot 1M | Qr 2M | Kr 512K | Vrt 512K | AO 2M

#define SEQ 2048
#define DM 1024
#define HD 64

using u16 = unsigned short;
typedef __attribute__((ext_vector_type(8))) short bf16x8;
typedef __attribute__((ext_vector_type(4))) float f32x4;

// 1/sqrt(64) * log2(e): softmax in exp2 domain.
#define QSCALE 0.18033688011112042f

__device__ __forceinline__ u16 f2b(float f) {              // RNE
    union { float f; unsigned int i; } v; v.f = f;
    unsigned int u = v.i;
    return (u16)((u + 0x7fffu + ((u >> 16) & 1u)) >> 16);
}
__device__ __forceinline__ u16 f2b_fast(float f) {         // biased round
    union { float f; unsigned int i; } v; v.f = f;
    return (u16)((v.i + 0x8000u) >> 16);
}

// ---------------------------------------------------------------- prep (r9)
// [0,640): weight 64x64 transposes fp32->bf16 row-major [n][k].
// [640,1408): q/k/v fp32 -> bf16 row-major.
__global__ __launch_bounds__(256) void prep_kernel(
    const float* __restrict__ qin, const float* __restrict__ kin, const float* __restrict__ vin,
    const float* __restrict__ Wq, const float* __restrict__ Wk,
    const float* __restrict__ Wv, const float* __restrict__ Wo,
    u16* __restrict__ Xq, u16* __restrict__ Xk, u16* __restrict__ Xv,
    u16* __restrict__ Wt, u16* __restrict__ wot)
{
    const int b = blockIdx.x;
    const int t = threadIdx.x;

    if (b < 640) {
        __shared__ short T[64][72];
        const float* W; u16* dst; int N, t0, rowoff;
        if (b < 256)      { W = Wq; dst = Wt;  N = 1024; t0 = b;       rowoff = 0; }
        else if (b < 320) { W = Wk; dst = Wt;  N = 256;  t0 = b - 256; rowoff = 1024; }
        else if (b < 384) { W = Wv; dst = Wt;  N = 256;  t0 = b - 320; rowoff = 1280; }
        else              { W = Wo; dst = wot; N = 1024; t0 = b - 384; rowoff = 0; }
        const int ntn = N >> 6;
        const int k0 = (t0 / ntn) * 64, n0 = (t0 % ntn) * 64;
        const int r = t >> 4, c4 = (t & 15) * 4;
        #pragma unroll
        for (int rr = 0; rr < 4; ++rr) {
            const int k = r + rr * 16;
            float4 w4 = *reinterpret_cast<const float4*>(W + (size_t)(k0 + k) * N + n0 + c4);
            T[c4 + 0][k] = (short)f2b(w4.x);
            T[c4 + 1][k] = (short)f2b(w4.y);
            T[c4 + 2][k] = (short)f2b(w4.z);
            T[c4 + 3][k] = (short)f2b(w4.w);
        }
        __syncthreads();
        const int n = t >> 2, ck = (t & 3) * 16;
        u16* dp = dst + (size_t)(rowoff + n0 + n) * DM + k0 + ck;
        *reinterpret_cast<bf16x8*>(dp)     = *reinterpret_cast<const bf16x8*>(&T[n][ck]);
        *reinterpret_cast<bf16x8*>(dp + 8) = *reinterpret_cast<const bf16x8*>(&T[n][ck + 8]);
    } else {
        const int idx = b - 640;
        const int which = idx >> 8;
        const int ib = idx & 255;
        const float* src = (which == 0) ? qin : (which == 1) ? kin : vin;
        u16* dst = (which == 0) ? Xq : (which == 1) ? Xk : Xv;
        const size_t base = (size_t)ib * 8192 + (size_t)t * 32;
        #pragma unroll
        for (int c = 0; c < 4; ++c) {
            float4 x0 = *reinterpret_cast<const float4*>(src + base + c * 8);
            float4 x1 = *reinterpret_cast<const float4*>(src + base + c * 8 + 4);
            bf16x8 o;
            o[0] = (short)f2b(x0.x); o[1] = (short)f2b(x0.y);
            o[2] = (short)f2b(x0.z); o[3] = (short)f2b(x0.w);
            o[4] = (short)f2b(x1.x); o[5] = (short)f2b(x1.y);
            o[6] = (short)f2b(x1.z); o[7] = (short)f2b(x1.w);
            *reinterpret_cast<bf16x8*>(dst + base + c * 8) = o;
        }
    }
}

// ---------------------------------------------------------------- projections
// Unified QKV: grid (12, 32), block tile 64m x 128n, BK=64, dbuf + reg
// prefetch, 1 barrier/iter. Wave tile 32x64 (acc[2][4], 16 MFMA / 12 b128).
// nt 0-7 = Q (RoPE*QSCALE), 8-9 = K (RoPE), 10-11 = V (transposed, key-perm).
__global__ __launch_bounds__(256) void proj_mfma(
    const u16* __restrict__ Xq, const u16* __restrict__ Xk, const u16* __restrict__ Xv,
    const u16* __restrict__ Wt,
    const float* __restrict__ bq, const float* __restrict__ bk, const float* __restrict__ bv,
    u16* __restrict__ Qr, u16* __restrict__ Kr, u16* __restrict__ Vrt)
{
    const int nt = blockIdx.x, mt = blockIdx.y;
    const int n0 = nt * 128, m0 = mt * 64;
    const int zone = (nt < 8) ? 0 : (nt < 10) ? 1 : 2;
    const u16* __restrict__ Az = (zone == 0) ? Xq : (zone == 1) ? Xk : Xv;

    __shared__ u16 As[2][64][72];      // A: 64 rows x 64 k
    __shared__ u16 Bs[2][128][72];     // B: 128 rows x 64 k

    const int t = threadIdx.x;
    const int w = t >> 6, lane = t & 63, lm = lane & 15, quad = lane >> 4;
    const int mh = w >> 1, nh = w & 1;          // wave: rows 32*mh.., cols 64*nh..

    const int asr = t >> 2, asc = (t & 3) * 16; // A staging: 2 b128/thread
    const int bsr = t >> 1, bsc = (t & 1) * 32; // B staging: 4 b128/thread

    f32x4 acc[2][4];
    #pragma unroll
    for (int i = 0; i < 2; ++i)
        #pragma unroll
        for (int j = 0; j < 4; ++j) acc[i][j] = (f32x4){0.f, 0.f, 0.f, 0.f};

    const u16* ap_ = Az + (size_t)(m0 + asr) * DM + asc;
    const u16* bp_ = Wt + (size_t)(n0 + bsr) * DM + bsc;
    bf16x8 aR0 = *reinterpret_cast<const bf16x8*>(ap_);
    bf16x8 aR1 = *reinterpret_cast<const bf16x8*>(ap_ + 8);
    bf16x8 bR0 = *reinterpret_cast<const bf16x8*>(bp_);
    bf16x8 bR1 = *reinterpret_cast<const bf16x8*>(bp_ + 8);
    bf16x8 bR2 = *reinterpret_cast<const bf16x8*>(bp_ + 16);
    bf16x8 bR3 = *reinterpret_cast<const bf16x8*>(bp_ + 24);

    for (int k0 = 0; k0 < DM; k0 += 64) {
        const int buf = (k0 >> 6) & 1;
        *reinterpret_cast<bf16x8*>(&As[buf][asr][asc])      = aR0;
        *reinterpret_cast<bf16x8*>(&As[buf][asr][asc + 8])  = aR1;
        *reinterpret_cast<bf16x8*>(&Bs[buf][bsr][bsc])      = bR0;
        *reinterpret_cast<bf16x8*>(&Bs[buf][bsr][bsc + 8])  = bR1;
        *reinterpret_cast<bf16x8*>(&Bs[buf][bsr][bsc + 16]) = bR2;
        *reinterpret_cast<bf16x8*>(&Bs[buf][bsr][bsc + 24]) = bR3;
        if (k0 + 64 < DM) {
            aR0 = *reinterpret_cast<const bf16x8*>(ap_ + k0 + 64);
            aR1 = *reinterpret_cast<const bf16x8*>(ap_ + k0 + 72);
            bR0 = *reinterpret_cast<const bf16x8*>(bp_ + k0 + 64);
            bR1 = *reinterpret_cast<const bf16x8*>(bp_ + k0 + 72);
            bR2 = *reinterpret_cast<const bf16x8*>(bp_ + k0 + 80);
            bR3 = *reinterpret_cast<const bf16x8*>(bp_ + k0 + 88);
        }
        __syncthreads();    // single barrier (dbuf-safe)
        bf16x8 af[2][2], bfr[4][2];
        #pragma unroll
        for (int ms = 0; ms < 2; ++ms)
            #pragma unroll
            for (int kh = 0; kh < 2; ++kh)
                af[ms][kh] = *reinterpret_cast<const bf16x8*>(
                    &As[buf][32 * mh + 16 * ms + lm][kh * 32 + quad * 8]);
        #pragma unroll
        for (int nb = 0; nb < 4; ++nb)
            #pragma unroll
            for (int kh = 0; kh < 2; ++kh)
                bfr[nb][kh] = *reinterpret_cast<const bf16x8*>(
                    &Bs[buf][64 * nh + 16 * nb + lm][kh * 32 + quad * 8]);
        #pragma unroll
        for (int ms = 0; ms < 2; ++ms)
            #pragma unroll
            for (int nb = 0; nb < 4; ++nb) {
                acc[ms][nb] = __builtin_amdgcn_mfma_f32_16x16x32_bf16(af[ms][0], bfr[nb][0], acc[ms][nb], 0, 0, 0);
                acc[ms][nb] = __builtin_amdgcn_mfma_f32_16x16x32_bf16(af[ms][1], bfr[nb][1], acc[ms][nb], 0, 0, 0);
            }
    }

    const float* __restrict__ bias = (zone == 0) ? bq : (zone == 1) ? bk : bv;
    const int zoff = (zone == 0) ? 0 : (zone == 1) ? 1024 : 1280;
    #pragma unroll
    for (int nb = 0; nb < 4; ++nb) {
        const int zc = (n0 - zoff) + 64 * nh + 16 * nb + lm;   // col within zone
        const int head = zc >> 6, d = zc & 63;
        const float bvv = bias[zc];
        if (zone != 2) {
            const int pi = d >> 1;
            const float theta = exp2f(-0.8304820237f * (float)pi);  // 10000^(-pi/16)
            const bool odd = (lm & 1);
            const float sca = (zone == 0) ? QSCALE : 1.0f;
            u16* op = (zone == 0 ? Qr : Kr) + (size_t)head * SEQ * HD;
            #pragma unroll
            for (int ms = 0; ms < 2; ++ms)
                #pragma unroll
                for (int r = 0; r < 4; ++r) {
                    const int m = m0 + 32 * mh + 16 * ms + quad * 4 + r;
                    float x = acc[ms][nb][r] + bvv;
                    float sn, cs;
                    sincosf((float)m * theta, &sn, &cs);
                    float xp = __shfl_xor(x, 1);
                    float o  = (odd ? (xp * sn + x * cs) : (x * cs - xp * sn)) * sca;
                    op[(size_t)m * HD + d] = f2b(o);
                }
        } else {
            // V transposed [kvh][d][pos], key-permuted per 64-tile:
            // within = m&63 -> pos = tile*64 + 4*(within&15) + (within>>4)
            u16* vp = Vrt + ((size_t)head * HD + d) * SEQ;
            #pragma unroll
            for (int ms = 0; ms < 2; ++ms)
                #pragma unroll
                for (int r = 0; r < 4; ++r) {
                    const int m = m0 + 32 * mh + 16 * ms + quad * 4 + r;
                    const int within = m & 63;
                    const int pos = (m & ~63) + 4 * (within & 15) + (within >> 4);
                    vp[pos] = f2b(acc[ms][nb][r] + bvv);
                }
        }
    }
}

// ---------------------------------------------------------------- attention (r9)
// grid (16 heads, 16 qy), 512 threads (8 waves, 2 teams of 4).
// Team 0: q-tile qy; team 1: q-tile 31-qy (constant 33 tile-computations).
// K/V staged once per kt for both teams (dbuf, 1 barrier/tile, reg prefetch).
// P: packed col-permuted LDS (c = 4*lm + nb) -> ds_write_b64; V global layout
// is key-permuted to match. Fixed-base exp2 softmax.
__global__ __launch_bounds__(512) void attn_mfma(
    const u16* __restrict__ Qr, const u16* __restrict__ Kr, const u16* __restrict__ Vrt,
    u16* __restrict__ AO)
{
    const int h  = blockIdx.x;
    const int qy = blockIdx.y;
    const int kvh = h & 3;

    __shared__ u16 Ks[2][64][72];     // [key][d]
    __shared__ u16 Vt[2][64][72];     // [d][c]  (c = permuted key)
    __shared__ u16 Ps[8][16][76];     // per-wave strip; also Q staging

    const int t = threadIdx.x;
    const int w = t >> 6, lane = t & 63, lm = lane & 15, quad = lane >> 4;
    const int team = w >> 2, wt = w & 3;
    const int qt  = team ? (31 - qy) : qy;
    const int qtb = 31 - qy;                      // = max(qt of both teams)

    {   // stage this wave's 16 Q rows into its Ps strip (wave-private)
        const int row = lane >> 2, c = (lane & 3) * 16;
        const u16* qp = Qr + ((size_t)h * SEQ + qt * 64 + wt * 16 + row) * HD + c;
        *reinterpret_cast<bf16x8*>(&Ps[w][row][c])     = *reinterpret_cast<const bf16x8*>(qp);
        *reinterpret_cast<bf16x8*>(&Ps[w][row][c + 8]) = *reinterpret_cast<const bf16x8*>(qp + 8);
    }
    const bf16x8 aq0 = *reinterpret_cast<const bf16x8*>(&Ps[w][lm][quad * 8]);
    const bf16x8 aq1 = *reinterpret_cast<const bf16x8*>(&Ps[w][lm][32 + quad * 8]);

    f32x4 O[4] = { {0,0,0,0}, {0,0,0,0}, {0,0,0,0}, {0,0,0,0} };   // C[q=quad*4+r][d=16db+lm]
    float lp[4] = { 0.f, 0.f, 0.f, 0.f };

    // staging: 512 threads, 1 b128 each for K and V
    const int srow = t >> 3, sc2 = (t & 7) * 8;
    const u16* kb_ = Kr  + ((size_t)kvh * SEQ + srow) * HD + sc2;   // + kt*64*HD
    const u16* vb_ = Vrt + ((size_t)kvh * HD + srow) * SEQ + sc2;   // + kt*64
    bf16x8 kR = *reinterpret_cast<const bf16x8*>(kb_);
    bf16x8 vR = *reinterpret_cast<const bf16x8*>(vb_);

    for (int kt = 0; kt <= qtb; ++kt) {
        const int buf = kt & 1;
        *reinterpret_cast<bf16x8*>(&Ks[buf][srow][sc2]) = kR;
        *reinterpret_cast<bf16x8*>(&Vt[buf][srow][sc2]) = vR;
        if (kt < qtb) {
            kR = *reinterpret_cast<const bf16x8*>(kb_ + (size_t)(kt + 1) * 64 * HD);
            vR = *reinterpret_cast<const bf16x8*>(vb_ + (size_t)(kt + 1) * 64);
        }
        __syncthreads();

        if (kt <= qt) {
            f32x4 s[4];
            #pragma unroll
            for (int nb = 0; nb < 4; ++nb) {
                bf16x8 b0 = *reinterpret_cast<const bf16x8*>(&Ks[buf][16 * nb + lm][quad * 8]);
                bf16x8 b1 = *reinterpret_cast<const bf16x8*>(&Ks[buf][16 * nb + lm][32 + quad * 8]);
                f32x4 zz = { 0.f, 0.f, 0.f, 0.f };
                zz = __builtin_amdgcn_mfma_f32_16x16x32_bf16(aq0, b0, zz, 0, 0, 0);
                s[nb] = __builtin_amdgcn_mfma_f32_16x16x32_bf16(aq1, b1, zz, 0, 0, 0);
            }

            if (kt == qt) {   // causal mask (col=16nb+lm, row=16wt+quad*4+r)
                #pragma unroll
                for (int nb = 0; nb < 4; ++nb)
                    #pragma unroll
                    for (int r = 0; r < 4; ++r)
                        if (16 * nb + lm > 16 * wt + quad * 4 + r) s[nb][r] = -INFINITY;
            }

            // exp2 + packed P write: row quad*4+r, cols c=4*lm..4*lm+3 (nb)
            #pragma unroll
            for (int r = 0; r < 4; ++r) {
                u16 pk[4];
                #pragma unroll
                for (int nb = 0; nb < 4; ++nb) {
                    float e = __builtin_amdgcn_exp2f(fminf(s[nb][r], 126.f));
                    lp[r] += e;
                    pk[nb] = f2b_fast(e);
                }
                *reinterpret_cast<uint2*>(&Ps[w][quad * 4 + r][4 * lm]) =
                    *reinterpret_cast<uint2*>(pk);
            }

            const bf16x8 ap0 = *reinterpret_cast<const bf16x8*>(&Ps[w][lm][quad * 8]);
            const bf16x8 ap1 = *reinterpret_cast<const bf16x8*>(&Ps[w][lm][32 + quad * 8]);
            #pragma unroll
            for (int db = 0; db < 4; ++db) {
                bf16x8 v0 = *reinterpret_cast<const bf16x8*>(&Vt[buf][16 * db + lm][quad * 8]);
                bf16x8 v1 = *reinterpret_cast<const bf16x8*>(&Vt[buf][16 * db + lm][32 + quad * 8]);
                O[db] = __builtin_amdgcn_mfma_f32_16x16x32_bf16(ap0, v0, O[db], 0, 0, 0);
                O[db] = __builtin_amdgcn_mfma_f32_16x16x32_bf16(ap1, v1, O[db], 0, 0, 0);
            }
        }
    }

    #pragma unroll
    for (int r = 0; r < 4; ++r) {
        #pragma unroll
        for (int off = 1; off < 16; off <<= 1)
            lp[r] += __shfl_xor(lp[r], off);
        const float inv = 1.0f / lp[r];
        const size_t row = (size_t)(qt * 64 + 16 * wt + quad * 4 + r) * DM + (size_t)h * HD;
        #pragma unroll
        for (int db = 0; db < 4; ++db)
            AO[row + 16 * db + lm] = f2b(O[db][r] * inv);
    }
}

// ---------------------------------------------------------------- output proj
// grid (8, 32): block tile 64m x 128n, wave 32x64, BK=64, dbuf, 1 barrier.
__global__ __launch_bounds__(256) void oproj_mfma(
    const u16* __restrict__ AO, const u16* __restrict__ wot,
    const float* __restrict__ bo, float* __restrict__ out)
{
    const int nt = blockIdx.x, mt = blockIdx.y;
    const int n0 = nt * 128, m0 = mt * 64;

    __shared__ u16 As[2][64][72];
    __shared__ u16 Bs[2][128][72];

    const int t = threadIdx.x;
    const int w = t >> 6, lane = t & 63, lm = lane & 15, quad = lane >> 4;
    const int mh = w >> 1, nh = w & 1;

    const int asr = t >> 2, asc = (t & 3) * 16;
    const int bsr = t >> 1, bsc = (t & 1) * 32;

    f32x4 acc[2][4];
    #pragma unroll
    for (int i = 0; i < 2; ++i)
        #pragma unroll
        for (int j = 0; j < 4; ++j) acc[i][j] = (f32x4){0.f, 0.f, 0.f, 0.f};

    const u16* ap_ = AO  + (size_t)(m0 + asr) * DM + asc;
    const u16* bp_ = wot + (size_t)(n0 + bsr) * DM + bsc;
    bf16x8 aR0 = *reinterpret_cast<const bf16x8*>(ap_);
    bf16x8 aR1 = *reinterpret_cast<const bf16x8*>(ap_ + 8);
    bf16x8 bR0 = *reinterpret_cast<const bf16x8*>(bp_);
    bf16x8 bR1 = *reinterpret_cast<const bf16x8*>(bp_ + 8);
    bf16x8 bR2 = *reinterpret_cast<const bf16x8*>(bp_ + 16);
    bf16x8 bR3 = *reinterpret_cast<const bf16x8*>(bp_ + 24);

    for (int k0 = 0; k0 < DM; k0 += 64) {
        const int buf = (k0 >> 6) & 1;
        *reinterpret_cast<bf16x8*>(&As[buf][asr][asc])      = aR0;
        *reinterpret_cast<bf16x8*>(&As[buf][asr][asc + 8])  = aR1;
        *reinterpret_cast<bf16x8*>(&Bs[buf][bsr][bsc])      = bR0;
        *reinterpret_cast<bf16x8*>(&Bs[buf][bsr][bsc + 8])  = bR1;
        *reinterpret_cast<bf16x8*>(&Bs[buf][bsr][bsc + 16]) = bR2;
        *reinterpret_cast<bf16x8*>(&Bs[buf][bsr][bsc + 24]) = bR3;
        if (k0 + 64 < DM) {
            aR0 = *reinterpret_cast<const bf16x8*>(ap_ + k0 + 64);
            aR1 = *reinterpret_cast<const bf16x8*>(ap_ + k0 + 72);
            bR0 = *reinterpret_cast<const bf16x8*>(bp_ + k0 + 64);
            bR1 = *reinterpret_cast<const bf16x8*>(bp_ + k0 + 72);
            bR2 = *reinterpret_cast<const bf16x8*>(bp_ + k0 + 80);
            bR3 = *reinterpret_cast<const bf16x8*>(bp_ + k0 + 88);
        }
        __syncthreads();
        bf16x8 af[2][2], bfr[4][2];
        #pragma unroll
        for (int ms = 0; ms < 2; ++ms)
            #pragma unroll
            for (int kh = 0; kh < 2; ++kh)
                af[ms][kh] = *reinterpret_cast<const bf16x8*>(
                    &As[buf][32 * mh + 16 * ms + lm][kh * 32 + quad * 8]);
        #pragma unroll
        for (int nb = 0; nb < 4; ++nb)
            #pragma unroll
            for (int kh = 0; kh < 2; ++kh)
                bfr[nb][kh] = *reinterpret_cast<const bf16x8*>(
                    &Bs[buf][64 * nh + 16 * nb + lm][kh * 32 + quad * 8]);
        #pragma unroll
        for (int ms = 0; ms < 2; ++ms)
            #pragma unroll
            for (int nb = 0; nb < 4; ++nb) {
                acc[ms][nb] = __builtin_amdgcn_mfma_f32_16x16x32_bf16(af[ms][0], bfr[nb][0], acc[ms][nb], 0, 0, 0);
                acc[ms][nb] = __builtin_amdgcn_mfma_f32_16x16x32_bf16(af[ms][1], bfr[nb][1], acc[ms][nb], 0, 0, 0);
            }
    }

    #pragma unroll
    for (int nb = 0; nb < 4; ++nb) {
        const int col = n0 + 64 * nh + 16 * nb + lm;
        const float bvv = bo[col];
        #pragma unroll
        for (int ms = 0; ms < 2; ++ms)
            #pragma unroll
            for (int r = 0; r < 4; ++r) {
                const int m = m0 + 32 * mh + 16 * ms + quad * 4 + r;
                out[(size_t)m * DM + col] = acc[ms][nb][r] + bvv;
            }
    }
}

// ---------------------------------------------------------------- launcher
extern "C" void kernel_launch(void* const* d_in, const int* in_sizes, int n_in,
                              void* d_out, int out_size, void* d_ws, size_t ws_size,
                              hipStream_t stream)
{
    const float* q  = (const float*)d_in[0];
    const float* k  = (const float*)d_in[1];
    const float* v  = (const float*)d_in[2];
    // d_in[3] = mask (int32) — causal tril, handled analytically
    const float* Wq = (const float*)d_in[4];
    const float* bq = (const float*)d_in[5];
    const float* Wk = (const float*)d_in[6];
    const float* bk = (const float*)d_in[7];
    const float* Wv = (const float*)d_in[8];
    const float* bv = (const float*)d_in[9];
    const float* Wo = (const float*)d_in[10];
    const float* bo = (const float*)d_in[11];
    float* out = (float*)d_out;

    u16* Xq  = (u16*)d_ws;                          // [2048][1024] bf16
    u16* Xk  = Xq  + (size_t)SEQ * DM;
    u16* Xv  = Xk  + (size_t)SEQ * DM;
    u16* Wt  = Xv  + (size_t)SEQ * DM;              // [1536][1024]
    u16* wot = Wt  + (size_t)1536 * 1024;           // [1024][1024]
    u16* Qr  = wot + (size_t)1024 * 1024;           // [16][2048][64]
    u16* Kr  = Qr  + (size_t)16 * SEQ * HD;         // [4][2048][64]
    u16* Vrt = Kr  + (size_t)4 * SEQ * HD;          // [4][64][2048] key-permuted
    u16* AO  = Vrt + (size_t)4 * SEQ * HD;          // [2048][1024]

    hipLaunchKernelGGL(prep_kernel, dim3(1408), dim3(256), 0, stream,
                       q, k, v, Wq, Wk, Wv, Wo, Xq, Xk, Xv, Wt, wot);
    hipLaunchKernelGGL(proj_mfma, dim3(12, 32), dim3(256), 0, stream,
                       Xq, Xk, Xv, Wt, bq, bk, bv, Qr, Kr, Vrt);
    hipLaunchKernelGGL(attn_mfma, dim3(16, 16), dim3(512), 0, stream,
                       Qr, Kr, Vrt, AO);
    hipLaunchKernelGGL(oproj_mfma, dim3(8, 32), dim3(256), 0, stream,
                       AO, wot, bo, out);
}